// Round 1
// baseline (1155.886 us; speedup 1.0000x reference)
//
#include <hip/hip_runtime.h>

// ---- problem constants (fixed shapes from setup_inputs) ----
#define H       128
#define MAXNB   10
#define M_TREE  32768
#define NBOND   262144
#define NATOM   131072
#define FATOM   35
#define FBOND   40      // ATOM_FDIM + BOND_FDIM
#define FOUT    163     // ATOM_FDIM + HIDDEN
#define NMOLS   4096
#define APM     32      // atoms per molecule (A / n_mols)
#define TB      128     // bonds per block in mp_step

typedef __bf16 bf16x8 __attribute__((ext_vector_type(8)));
typedef float  f32x4  __attribute__((ext_vector_type(4)));

__device__ __forceinline__ unsigned short f32_to_bf16(float f) {
  unsigned int u = __float_as_uint(f);
  u += 0x7FFFu + ((u >> 16) & 1u);   // round-to-nearest-even (inputs have no NaN)
  return (unsigned short)(u >> 16);
}
__device__ __forceinline__ float bf16u_to_f32(unsigned short h) {
  return __uint_as_float(((unsigned int)h) << 16);
}

// ---- prep: convert tree_message and W_h to bf16 in workspace ----
__global__ __launch_bounds__(256) void prep(const float* __restrict__ tm,
                                            const float* __restrict__ wh,
                                            unsigned short* __restrict__ tmsg,
                                            unsigned short* __restrict__ whb) {
  int i = blockIdx.x * 256 + threadIdx.x;
  const int n1 = M_TREE * H;               // 4,194,304
  if (i < n1) {
    tmsg[i] = f32_to_bf16(tm[i]);
  } else {
    int j = i - n1;
    if (j < H * H) whb[j] = f32_to_bf16(wh[j]);
  }
}

// ---- h0 = relu(bond_feats @ W_i^T), stored bf16 ----
__global__ __launch_bounds__(256) void wi_gemm(const float* __restrict__ bond_feats,
                                               const float* __restrict__ W_i,
                                               unsigned short* __restrict__ h0) {
  __shared__ float sW[128 * 41];   // W_i padded stride 41 (bank spread)
  __shared__ float sF[16 * 40];    // 16 bond rows
  const int t = threadIdx.x;
  const int base = blockIdx.x * 16;

  for (int i = t; i < 128 * 40; i += 256) {
    int h = i / 40, f = i - h * 40;
    sW[h * 41 + f] = W_i[i];
  }
  for (int i = t; i < 16 * 40; i += 256) sF[i] = bond_feats[base * 40 + i];
  __syncthreads();

  const int h = t & 127;
  const int grp = t >> 7;          // 0..1 -> 8 bonds each
  float acc[8] = {0.f,0.f,0.f,0.f,0.f,0.f,0.f,0.f};
  const float* wrow = &sW[h * 41];
  for (int f = 0; f < 40; ++f) {
    float w = wrow[f];
#pragma unroll
    for (int k = 0; k < 8; ++k) acc[k] += w * sF[(grp * 8 + k) * 40 + f];
  }
#pragma unroll
  for (int k = 0; k < 8; ++k) {
    float v = fmaxf(acc[k], 0.f);
    h0[(base + grp * 8 + k) * H + h] = f32_to_bf16(v);
  }
}

// ---- one message-passing round: gm_out = relu(h0 + gather(gm_in)@W_h^T) ----
__global__ __launch_bounds__(256) void mp_step(const unsigned short* __restrict__ gm_in,
                                               unsigned short* __restrict__ gm_out,
                                               const unsigned short* __restrict__ h0,
                                               const unsigned short* __restrict__ tmsg,
                                               const int* __restrict__ bond_graph,
                                               const unsigned short* __restrict__ whb) {
  // nei tile, padded to 136 bf16/row -> 2-way bank alias only (free per m136)
  __shared__ unsigned short snei[TB][H + 8];
  const int t = threadIdx.x;
  const int lane = t & 63;
  const int wave = t >> 6;
  const int b0 = blockIdx.x * TB;

  // ---- gather: wave handles bonds wave, wave+4, ... ; lane owns cols 2l,2l+1 ----
  for (int lb = wave; lb < TB; lb += 4) {
    const int b = b0 + lb;
    const int* bg = bond_graph + b * MAXNB;
    const unsigned short* rows[MAXNB];
#pragma unroll
    for (int j = 0; j < MAXNB; ++j) {
      int idx = bg[j];   // wave-uniform
      rows[j] = (idx < M_TREE) ? (tmsg + idx * H) : (gm_in + (idx - M_TREE) * H);
    }
    unsigned int u[MAXNB];
#pragma unroll
    for (int j = 0; j < MAXNB; ++j)
      u[j] = *(const unsigned int*)(rows[j] + 2 * lane);   // 10 loads in flight
    float a0 = 0.f, a1 = 0.f;
#pragma unroll
    for (int j = 0; j < MAXNB; ++j) {
      a0 += __uint_as_float(u[j] << 16);
      a1 += __uint_as_float(u[j] & 0xFFFF0000u);
    }
    unsigned int packed = ((unsigned int)f32_to_bf16(a1) << 16) | (unsigned int)f32_to_bf16(a0);
    *(unsigned int*)&snei[lb][2 * lane] = packed;
  }

  // ---- W_h^T fragments fully register-resident (32 frags = 128 VGPRs) ----
  // B[k][n] = W_h[g=n][k]; lane holds B[kt*32+quad*8+j][nt*16+(lane&15)]
  const int n16 = lane & 15;
  const int quad = lane >> 4;
  bf16x8 Bf[4][8];
#pragma unroll
  for (int kt = 0; kt < 4; ++kt)
#pragma unroll
    for (int nt = 0; nt < 8; ++nt)
      Bf[kt][nt] = *(const bf16x8*)(whb + (nt * 16 + n16) * H + kt * 32 + quad * 8);

  __syncthreads();

  // ---- MFMA: wave owns m-tiles 2w, 2w+1 (16 bonds each) ----
  f32x4 zero = {0.f, 0.f, 0.f, 0.f};
  f32x4 acc[2][8];
#pragma unroll
  for (int mt = 0; mt < 2; ++mt)
#pragma unroll
    for (int nt = 0; nt < 8; ++nt) acc[mt][nt] = zero;

#pragma unroll
  for (int kt = 0; kt < 4; ++kt) {
    bf16x8 av[2];
#pragma unroll
    for (int mt = 0; mt < 2; ++mt) {
      int m = (wave * 2 + mt) * 16 + n16;       // A[m=lane&15][k=quad*8+j]
      av[mt] = *(const bf16x8*)&snei[m][kt * 32 + quad * 8];
    }
#pragma unroll
    for (int nt = 0; nt < 8; ++nt) {
      acc[0][nt] = __builtin_amdgcn_mfma_f32_16x16x32_bf16(av[0], Bf[kt][nt], acc[0][nt], 0, 0, 0);
      acc[1][nt] = __builtin_amdgcn_mfma_f32_16x16x32_bf16(av[1], Bf[kt][nt], acc[1][nt], 0, 0, 0);
    }
  }

  // ---- epilogue: relu(h0 + acc); C/D layout col=lane&15, row=quad*4+reg ----
#pragma unroll
  for (int mt = 0; mt < 2; ++mt) {
    const int bb = b0 + (wave * 2 + mt) * 16;
#pragma unroll
    for (int nt = 0; nt < 8; ++nt) {
      const int col = nt * 16 + n16;
#pragma unroll
      for (int r = 0; r < 4; ++r) {
        const int b = bb + quad * 4 + r;
        float hv = bf16u_to_f32(h0[b * H + col]);
        float v = fmaxf(hv + acc[mt][nt][r], 0.f);
        gm_out[b * H + col] = f32_to_bf16(v);
      }
    }
  }
}

// ---- readout: per-molecule block; gather atoms, W_o GEMM, mean over 32 atoms ----
__global__ __launch_bounds__(256) void readout(const float* __restrict__ atom_feats,
                                               const unsigned short* __restrict__ gm,
                                               const unsigned short* __restrict__ tmsg,
                                               const int* __restrict__ atom_graph,
                                               const float* __restrict__ W_o,
                                               const float* __restrict__ b_o,
                                               float* __restrict__ out) {
  __shared__ float sIn[APM][FATOM + H + 5];          // [32][168] f32 = 21504 B
  __shared__ unsigned short sWoT[FOUT][130];         // W_o^T bf16 padded = 42380 B
  __shared__ float sAcc[H];                          // 512 B  (total 64396 < 64K)
  const int t = threadIdx.x;
  const int lane = t & 63;
  const int wave = t >> 6;
  const int mol = blockIdx.x;
  const int abase = mol * APM;

  if (t < H) sAcc[t] = 0.f;
  // stage W_o transposed (bf16)
  for (int i = t; i < H * FOUT; i += 256) {
    int g = i / FOUT, k = i - g * FOUT;
    sWoT[k][g] = f32_to_bf16(W_o[i]);
  }
  // stage atom features (cols 0..34)
  for (int i = t; i < APM * FATOM; i += 256) {
    int a = i / FATOM, f = i - a * FATOM;
    sIn[a][f] = atom_feats[(abase + a) * FATOM + f];
  }
  // gather neighbor-message sums (cols 35..162)
  for (int la = wave; la < APM; la += 4) {
    const int* ag = atom_graph + (abase + la) * MAXNB;
    const unsigned short* rows[MAXNB];
#pragma unroll
    for (int j = 0; j < MAXNB; ++j) {
      int idx = ag[j];
      rows[j] = (idx < M_TREE) ? (tmsg + idx * H) : (gm + (idx - M_TREE) * H);
    }
    unsigned int u[MAXNB];
#pragma unroll
    for (int j = 0; j < MAXNB; ++j)
      u[j] = *(const unsigned int*)(rows[j] + 2 * lane);
    float a0 = 0.f, a1 = 0.f;
#pragma unroll
    for (int j = 0; j < MAXNB; ++j) {
      a0 += __uint_as_float(u[j] << 16);
      a1 += __uint_as_float(u[j] & 0xFFFF0000u);
    }
    sIn[la][FATOM + 2 * lane]     = a0;
    sIn[la][FATOM + 2 * lane + 1] = a1;
  }
  __syncthreads();

  // GEMM: 32 atoms x 128 g, K=163. thread = 4 atoms x 4 g
  const int g0 = (t & 31) * 4;
  const int a0i = (t >> 5) * 4;
  float acc[4][4] = {{0.f}};
  for (int k = 0; k < FOUT; ++k) {
    float w[4], x[4];
#pragma unroll
    for (int q = 0; q < 4; ++q) w[q] = bf16u_to_f32(sWoT[k][g0 + q]);
#pragma unroll
    for (int q = 0; q < 4; ++q) x[q] = sIn[a0i + q][k];
#pragma unroll
    for (int ai = 0; ai < 4; ++ai)
#pragma unroll
      for (int gi = 0; gi < 4; ++gi) acc[ai][gi] += x[ai] * w[gi];
  }
  float ps[4] = {0.f, 0.f, 0.f, 0.f};
#pragma unroll
  for (int gi = 0; gi < 4; ++gi) {
    float bo = b_o[g0 + gi];
#pragma unroll
    for (int ai = 0; ai < 4; ++ai) ps[gi] += fmaxf(acc[ai][gi] + bo, 0.f);
  }
#pragma unroll
  for (int gi = 0; gi < 4; ++gi) atomicAdd(&sAcc[g0 + gi], ps[gi]);
  __syncthreads();
  if (t < H) out[mol * H + t] = sAcc[t] * (1.0f / APM);
}

extern "C" void kernel_launch(void* const* d_in, const int* in_sizes, int n_in,
                              void* d_out, int out_size, void* d_ws, size_t ws_size,
                              hipStream_t stream) {
  (void)in_sizes; (void)n_in; (void)out_size; (void)ws_size;
  const float* atom_feats   = (const float*)d_in[0];
  const float* bond_feats   = (const float*)d_in[1];
  const float* tree_message = (const float*)d_in[2];
  const int*   atom_graph   = (const int*)d_in[3];
  const int*   bond_graph   = (const int*)d_in[4];
  // d_in[5] = n_mols (fixed 4096)
  const float* W_i = (const float*)d_in[6];
  const float* W_h = (const float*)d_in[7];
  const float* W_o = (const float*)d_in[8];
  const float* b_o = (const float*)d_in[9];
  float* out = (float*)d_out;

  char* ws = (char*)d_ws;
  unsigned short* tmsg = (unsigned short*)(ws);                    //  8,388,608 B
  unsigned short* whb  = (unsigned short*)(ws + 8388608);          //     32,768 B
  unsigned short* h0   = (unsigned short*)(ws + 8421376);          // 67,108,864 B
  unsigned short* gm0  = (unsigned short*)(ws + 75530240);         // 67,108,864 B
  unsigned short* gm1  = (unsigned short*)(ws + 142639104);        // 67,108,864 B
  // total ws use: 209,747,968 B

  prep<<<16448, 256, 0, stream>>>(tree_message, W_h, tmsg, whb);
  wi_gemm<<<NBOND / 16, 256, 0, stream>>>(bond_feats, W_i, h0);
  // 5 rounds, ping-pong; round 0 reads h0 as graph_message
  mp_step<<<NBOND / TB, 256, 0, stream>>>(h0,  gm0, h0, tmsg, bond_graph, whb);
  mp_step<<<NBOND / TB, 256, 0, stream>>>(gm0, gm1, h0, tmsg, bond_graph, whb);
  mp_step<<<NBOND / TB, 256, 0, stream>>>(gm1, gm0, h0, tmsg, bond_graph, whb);
  mp_step<<<NBOND / TB, 256, 0, stream>>>(gm0, gm1, h0, tmsg, bond_graph, whb);
  mp_step<<<NBOND / TB, 256, 0, stream>>>(gm1, gm0, h0, tmsg, bond_graph, whb);
  readout<<<NMOLS, 256, 0, stream>>>(atom_feats, gm0, tmsg, atom_graph, W_o, b_o, out);
}

// Round 2
// 866.357 us; speedup vs baseline: 1.3342x; 1.3342x over previous
//
#include <hip/hip_runtime.h>

// ---- problem constants (fixed shapes from setup_inputs) ----
#define H       128
#define MAXNB   10
#define M_TREE  32768
#define NBOND   262144
#define NATOM   131072
#define FATOM   35
#define FBOND   40      // ATOM_FDIM + BOND_FDIM
#define FOUT    163     // ATOM_FDIM + HIDDEN
#define KPAD    192     // FOUT padded (with one zero col inserted at 35) to 6 k-tiles
#define NMOLS   4096
#define APM     32      // atoms per molecule
#define TB      128     // bonds per block in mp_step

typedef __bf16 bf16x8 __attribute__((ext_vector_type(8)));
typedef float  f32x4  __attribute__((ext_vector_type(4)));

__device__ __forceinline__ unsigned short f32_to_bf16(float f) {
  unsigned int u = __float_as_uint(f);
  u += 0x7FFFu + ((u >> 16) & 1u);   // RNE (inputs have no NaN)
  return (unsigned short)(u >> 16);
}
__device__ __forceinline__ float bf16u_to_f32(unsigned short h) {
  return __uint_as_float(((unsigned int)h) << 16);
}

// ---- prep: bf16 conversions + padded weight layouts ----
// tmsg   [M_TREE][128]  bf16
// whb    [128][128]     bf16 (W_h as-is, g-major)
// W_ob   [128][192]     bf16: k<35 -> W_o[g][k]; k==35 -> 0; 36<=k<164 -> W_o[g][k-1]; else 0
// W_ib   [128][64]      bf16: k<40 -> W_i[g][k]; else 0
__global__ __launch_bounds__(256) void prep(const float* __restrict__ tm,
                                            const float* __restrict__ wh,
                                            const float* __restrict__ wo,
                                            const float* __restrict__ wi,
                                            unsigned short* __restrict__ tmsg,
                                            unsigned short* __restrict__ whb,
                                            unsigned short* __restrict__ wob,
                                            unsigned short* __restrict__ wib) {
  int i = blockIdx.x * 256 + threadIdx.x;
  const int n1 = M_TREE * H;           // 4,194,304
  const int n2 = H * H;                // 16,384
  const int n3 = H * KPAD;             // 24,576
  const int n4 = H * 64;               // 8,192
  if (i < n1) { tmsg[i] = f32_to_bf16(tm[i]); return; }
  int j = i - n1;
  if (j < n2) { whb[j] = f32_to_bf16(wh[j]); return; }
  int k = j - n2;
  if (k < n3) {
    int g = k / KPAD, kk = k - g * KPAD;
    float v = 0.f;
    if (kk < 35)                 v = wo[g * FOUT + kk];
    else if (kk >= 36 && kk < 164) v = wo[g * FOUT + kk - 1];
    wob[k] = f32_to_bf16(v);
    return;
  }
  int m = k - n3;
  if (m < n4) {
    int g = m / 64, kk = m - g * 64;
    wib[m] = (kk < FBOND) ? f32_to_bf16(wi[g * FBOND + kk]) : (unsigned short)0;
  }
}

// ---- h0 = relu(bond_feats @ W_i^T), MFMA, stored bf16 ----
__global__ __launch_bounds__(256, 3) void wi_gemm(const float* __restrict__ bond_feats,
                                                  const unsigned short* __restrict__ wib,
                                                  unsigned short* __restrict__ h0) {
  __shared__ unsigned short sF[128][72];   // stride 144B: 16B aligned, 2-way banks (free)
  const int t = threadIdx.x;
  const int lane = t & 63;
  const int wave = t >> 6;
  const int n16 = lane & 15;
  const int quad = lane >> 4;
  const int b0 = blockIdx.x * 128;

  for (int i = t; i < 128 * FBOND; i += 256) {
    int b = i / FBOND, f = i - b * FBOND;
    sF[b][f] = f32_to_bf16(bond_feats[b0 * FBOND + i]);
  }
  for (int i = t; i < 128 * 24; i += 256) {   // zero pad cols 40..63
    int b = i / 24, c = 40 + i - b * 24;
    sF[b][c] = 0;
  }
  bf16x8 Bf[2][2];
#pragma unroll
  for (int kt = 0; kt < 2; ++kt)
#pragma unroll
    for (int nt = 0; nt < 2; ++nt)
      Bf[kt][nt] = *(const bf16x8*)(wib + ((wave * 2 + nt) * 16 + n16) * 64 + kt * 32 + quad * 8);
  __syncthreads();

  f32x4 acc[8][2];
  f32x4 zero = {0.f, 0.f, 0.f, 0.f};
#pragma unroll
  for (int mt = 0; mt < 8; ++mt) { acc[mt][0] = zero; acc[mt][1] = zero; }
#pragma unroll
  for (int kt = 0; kt < 2; ++kt)
#pragma unroll
    for (int mt = 0; mt < 8; ++mt) {
      bf16x8 av = *(const bf16x8*)&sF[mt * 16 + n16][kt * 32 + quad * 8];
      acc[mt][0] = __builtin_amdgcn_mfma_f32_16x16x32_bf16(av, Bf[kt][0], acc[mt][0], 0, 0, 0);
      acc[mt][1] = __builtin_amdgcn_mfma_f32_16x16x32_bf16(av, Bf[kt][1], acc[mt][1], 0, 0, 0);
    }
#pragma unroll
  for (int mt = 0; mt < 8; ++mt)
#pragma unroll
    for (int nt = 0; nt < 2; ++nt) {
      const int col = (wave * 2 + nt) * 16 + n16;
#pragma unroll
      for (int r = 0; r < 4; ++r) {
        const int b = b0 + mt * 16 + quad * 4 + r;
        h0[b * H + col] = f32_to_bf16(fmaxf(acc[mt][nt][r], 0.f));
      }
    }
}

// ---- one MP round: gm_out = relu(h0 + gather(msg)@W_h^T) ----
__global__ __launch_bounds__(256, 3) void mp_step(const unsigned short* __restrict__ gm_in,
                                                  unsigned short* __restrict__ gm_out,
                                                  const unsigned short* __restrict__ h0,
                                                  const unsigned short* __restrict__ tmsg,
                                                  const int* __restrict__ bond_graph,
                                                  const unsigned short* __restrict__ whb) {
  __shared__ unsigned short snei[TB][136];   // 16B-aligned stride, 2-way banks (free)
  __shared__ int sBG[TB * MAXNB];
  const int t = threadIdx.x;
  const int lane = t & 63;
  const int wave = t >> 6;
  const int n16 = lane & 15;
  const int quad = lane >> 4;
  const int b0 = blockIdx.x * TB;

  // stage indices (coalesced) — breaks the idx->row dependent global chain
  for (int i = t; i < TB * MAXNB; i += 256) sBG[i] = bond_graph[b0 * MAXNB + i];

  // W_h^T fragments, nt-split per wave: 8 frags = 32 VGPRs
  bf16x8 Bf[4][2];
#pragma unroll
  for (int kt = 0; kt < 4; ++kt)
#pragma unroll
    for (int nt = 0; nt < 2; ++nt)
      Bf[kt][nt] = *(const bf16x8*)(whb + ((wave * 2 + nt) * 16 + n16) * H + kt * 32 + quad * 8);
  __syncthreads();

  const unsigned short* gsh = gm_in - (size_t)M_TREE * H;  // shifted base for idx>=M
  // gather: 2 bonds per iteration -> 20 row-loads in flight
  for (int lb = wave * 2; lb < TB; lb += 8) {
    unsigned int u[2][MAXNB];
#pragma unroll
    for (int p = 0; p < 2; ++p) {
      const int* ig = &sBG[(lb + p) * MAXNB];
#pragma unroll
      for (int j = 0; j < MAXNB; ++j) {
        int idx = ig[j];
        const unsigned short* r = ((idx < M_TREE) ? tmsg : gsh) + (size_t)idx * H;
        u[p][j] = *(const unsigned int*)(r + 2 * lane);
      }
    }
#pragma unroll
    for (int p = 0; p < 2; ++p) {
      float a0 = 0.f, a1 = 0.f;
#pragma unroll
      for (int j = 0; j < MAXNB; ++j) {
        a0 += __uint_as_float(u[p][j] << 16);
        a1 += __uint_as_float(u[p][j] & 0xFFFF0000u);
      }
      unsigned int packed = ((unsigned int)f32_to_bf16(a1) << 16) | (unsigned int)f32_to_bf16(a0);
      *(unsigned int*)&snei[lb + p][2 * lane] = packed;
    }
  }
  __syncthreads();

  f32x4 acc[8][2];
  f32x4 zero = {0.f, 0.f, 0.f, 0.f};
#pragma unroll
  for (int mt = 0; mt < 8; ++mt) { acc[mt][0] = zero; acc[mt][1] = zero; }
#pragma unroll
  for (int kt = 0; kt < 4; ++kt)
#pragma unroll
    for (int mt = 0; mt < 8; ++mt) {
      bf16x8 av = *(const bf16x8*)&snei[mt * 16 + n16][kt * 32 + quad * 8];
      acc[mt][0] = __builtin_amdgcn_mfma_f32_16x16x32_bf16(av, Bf[kt][0], acc[mt][0], 0, 0, 0);
      acc[mt][1] = __builtin_amdgcn_mfma_f32_16x16x32_bf16(av, Bf[kt][1], acc[mt][1], 0, 0, 0);
    }

  // epilogue: relu(h0 + acc); C/D: col=lane&15, row=quad*4+reg
#pragma unroll
  for (int mt = 0; mt < 8; ++mt)
#pragma unroll
    for (int nt = 0; nt < 2; ++nt) {
      const int col = (wave * 2 + nt) * 16 + n16;
#pragma unroll
      for (int r = 0; r < 4; ++r) {
        const int b = b0 + mt * 16 + quad * 4 + r;
        float hv = bf16u_to_f32(h0[b * H + col]);
        gm_out[b * H + col] = f32_to_bf16(fmaxf(hv + acc[mt][nt][r], 0.f));
      }
    }
}

// ---- readout: 128 atoms (4 mols)/block, MFMA over K=192, in-register mol reduce ----
__global__ __launch_bounds__(256, 3) void readout(const float* __restrict__ atom_feats,
                                                  const unsigned short* __restrict__ gm,
                                                  const unsigned short* __restrict__ tmsg,
                                                  const int* __restrict__ atom_graph,
                                                  const unsigned short* __restrict__ wob,
                                                  const float* __restrict__ b_o,
                                                  float* __restrict__ out) {
  __shared__ unsigned short sA[128][200];   // stride 400B: 16B aligned, 2-way banks
  __shared__ int sAG[128 * MAXNB];
  const int t = threadIdx.x;
  const int lane = t & 63;
  const int wave = t >> 6;
  const int n16 = lane & 15;
  const int quad = lane >> 4;
  const int blk = blockIdx.x;
  const int abase = blk * 128;

  for (int i = t; i < 128 * MAXNB; i += 256) sAG[i] = atom_graph[abase * MAXNB + i];
  // atom feats -> cols 0..34
  for (int i = t; i < 128 * FATOM; i += 256) {
    int a = i / FATOM, f = i - a * FATOM;
    sA[a][f] = f32_to_bf16(atom_feats[abase * FATOM + i]);
  }
  if (t < 128) sA[t][35] = 0;               // inserted zero col
  for (int i = t; i < 128 * 28; i += 256) { // zero cols 164..191
    int a = i / 28, c = 164 + i - a * 28;
    sA[a][c] = 0;
  }

  bf16x8 Bf[6][2];
#pragma unroll
  for (int kt = 0; kt < 6; ++kt)
#pragma unroll
    for (int nt = 0; nt < 2; ++nt)
      Bf[kt][nt] = *(const bf16x8*)(wob + ((wave * 2 + nt) * 16 + n16) * KPAD + kt * 32 + quad * 8);
  __syncthreads();

  const unsigned short* gsh = gm - (size_t)M_TREE * H;
  for (int la = wave * 2; la < 128; la += 8) {
    unsigned int u[2][MAXNB];
#pragma unroll
    for (int p = 0; p < 2; ++p) {
      const int* ig = &sAG[(la + p) * MAXNB];
#pragma unroll
      for (int j = 0; j < MAXNB; ++j) {
        int idx = ig[j];
        const unsigned short* r = ((idx < M_TREE) ? tmsg : gsh) + (size_t)idx * H;
        u[p][j] = *(const unsigned int*)(r + 2 * lane);
      }
    }
#pragma unroll
    for (int p = 0; p < 2; ++p) {
      float a0 = 0.f, a1 = 0.f;
#pragma unroll
      for (int j = 0; j < MAXNB; ++j) {
        a0 += __uint_as_float(u[p][j] << 16);
        a1 += __uint_as_float(u[p][j] & 0xFFFF0000u);
      }
      unsigned int packed = ((unsigned int)f32_to_bf16(a1) << 16) | (unsigned int)f32_to_bf16(a0);
      *(unsigned int*)&sA[la + p][36 + 2 * lane] = packed;   // nei -> cols 36..163
    }
  }
  __syncthreads();

  f32x4 acc[8][2];
  f32x4 zero = {0.f, 0.f, 0.f, 0.f};
#pragma unroll
  for (int mt = 0; mt < 8; ++mt) { acc[mt][0] = zero; acc[mt][1] = zero; }
#pragma unroll
  for (int kt = 0; kt < 6; ++kt)
#pragma unroll
    for (int mt = 0; mt < 8; ++mt) {
      bf16x8 av = *(const bf16x8*)&sA[mt * 16 + n16][kt * 32 + quad * 8];
      acc[mt][0] = __builtin_amdgcn_mfma_f32_16x16x32_bf16(av, Bf[kt][0], acc[mt][0], 0, 0, 0);
      acc[mt][1] = __builtin_amdgcn_mfma_f32_16x16x32_bf16(av, Bf[kt][1], acc[mt][1], 0, 0, 0);
    }

  // bias + relu per atom, then mol partial sums (atoms 32k..32k+31 -> mol k = mt>>1)
  float bo[2] = { b_o[(wave * 2) * 16 + n16], b_o[(wave * 2 + 1) * 16 + n16] };
  float part[4][2] = {{0.f,0.f},{0.f,0.f},{0.f,0.f},{0.f,0.f}};
#pragma unroll
  for (int mt = 0; mt < 8; ++mt)
#pragma unroll
    for (int nt = 0; nt < 2; ++nt)
#pragma unroll
      for (int r = 0; r < 4; ++r)
        part[mt >> 1][nt] += fmaxf(acc[mt][nt][r] + bo[nt], 0.f);
  // reduce across quads (lanes n16, n16+16, n16+32, n16+48)
#pragma unroll
  for (int mol = 0; mol < 4; ++mol)
#pragma unroll
    for (int nt = 0; nt < 2; ++nt) {
      float p = part[mol][nt];
      p += __shfl_xor(p, 16);
      p += __shfl_xor(p, 32);
      if (lane < 16)
        out[(blk * 4 + mol) * H + (wave * 2 + nt) * 16 + lane] = p * (1.0f / APM);
    }
}

extern "C" void kernel_launch(void* const* d_in, const int* in_sizes, int n_in,
                              void* d_out, int out_size, void* d_ws, size_t ws_size,
                              hipStream_t stream) {
  (void)in_sizes; (void)n_in; (void)out_size; (void)ws_size;
  const float* atom_feats   = (const float*)d_in[0];
  const float* bond_feats   = (const float*)d_in[1];
  const float* tree_message = (const float*)d_in[2];
  const int*   atom_graph   = (const int*)d_in[3];
  const int*   bond_graph   = (const int*)d_in[4];
  const float* W_i = (const float*)d_in[6];
  const float* W_h = (const float*)d_in[7];
  const float* W_o = (const float*)d_in[8];
  const float* b_o = (const float*)d_in[9];
  float* out = (float*)d_out;

  char* ws = (char*)d_ws;
  unsigned short* tmsg = (unsigned short*)(ws);                    //  8,388,608 B
  unsigned short* whb  = (unsigned short*)(ws + 8388608);          //     32,768 B
  unsigned short* wob  = (unsigned short*)(ws + 8421376);          //     49,152 B
  unsigned short* wib  = (unsigned short*)(ws + 8470528);          //     16,384 B
  unsigned short* h0   = (unsigned short*)(ws + 8486912);          // 67,108,864 B
  unsigned short* gm0  = (unsigned short*)(ws + 75595776);         // 67,108,864 B
  unsigned short* gm1  = (unsigned short*)(ws + 142704640);        // 67,108,864 B
  // total: 209,813,504 B

  prep<<<16576, 256, 0, stream>>>(tree_message, W_h, W_o, W_i, tmsg, whb, wob, wib);
  wi_gemm<<<NBOND / 128, 256, 0, stream>>>(bond_feats, wib, h0);
  mp_step<<<NBOND / TB, 256, 0, stream>>>(h0,  gm0, h0, tmsg, bond_graph, whb);
  mp_step<<<NBOND / TB, 256, 0, stream>>>(gm0, gm1, h0, tmsg, bond_graph, whb);
  mp_step<<<NBOND / TB, 256, 0, stream>>>(gm1, gm0, h0, tmsg, bond_graph, whb);
  mp_step<<<NBOND / TB, 256, 0, stream>>>(gm0, gm1, h0, tmsg, bond_graph, whb);
  mp_step<<<NBOND / TB, 256, 0, stream>>>(gm1, gm0, h0, tmsg, bond_graph, whb);
  readout<<<NATOM / 128, 256, 0, stream>>>(atom_feats, gm0, tmsg, atom_graph, wob, b_o, out);
}

// Round 5
// 812.374 us; speedup vs baseline: 1.4228x; 1.0665x over previous
//
#include <hip/hip_runtime.h>

// ---- problem constants (fixed shapes from setup_inputs) ----
#define H       128
#define MAXNB   10
#define M_TREE  32768
#define NBOND   262144
#define NATOM   131072
#define FATOM   35
#define FBOND   40      // ATOM_FDIM + BOND_FDIM
#define FOUT    163     // ATOM_FDIM + HIDDEN
#define KPAD    192     // FOUT padded (zero col at 35) to 6 k-tiles
#define NMOLS   4096
#define APM     32
#define TB      128     // bonds per block in mp_step

typedef __bf16 bf16x8 __attribute__((ext_vector_type(8)));
typedef float  f32x4  __attribute__((ext_vector_type(4)));
typedef unsigned int u32x4 __attribute__((ext_vector_type(4)));   // native vec for NT builtins

__device__ __forceinline__ unsigned short f32_to_bf16(float f) {
  unsigned int u = __float_as_uint(f);
  u += 0x7FFFu + ((u >> 16) & 1u);   // RNE (no NaN in this data)
  return (unsigned short)(u >> 16);
}
__device__ __forceinline__ float bf16u_to_f32(unsigned short h) {
  return __uint_as_float(((unsigned int)h) << 16);
}
// packed pair: relu(bf16(a) + bf16(h)) -> packed bf16
__device__ __forceinline__ unsigned int bfpair_addrelu(unsigned int a, unsigned int h) {
  float a0 = __uint_as_float(a << 16), a1 = __uint_as_float(a & 0xFFFF0000u);
  float h0v = __uint_as_float(h << 16), h1v = __uint_as_float(h & 0xFFFF0000u);
  float r0 = fmaxf(a0 + h0v, 0.f), r1 = fmaxf(a1 + h1v, 0.f);
  return ((unsigned int)f32_to_bf16(r1) << 16) | (unsigned int)f32_to_bf16(r0);
}

// ---- prep: bf16 conversions + padded weight layouts ----
__global__ __launch_bounds__(256) void prep(const float* __restrict__ tm,
                                            const float* __restrict__ wh,
                                            const float* __restrict__ wo,
                                            const float* __restrict__ wi,
                                            unsigned short* __restrict__ tmsg,
                                            unsigned short* __restrict__ whb,
                                            unsigned short* __restrict__ wob,
                                            unsigned short* __restrict__ wib) {
  int i = blockIdx.x * 256 + threadIdx.x;
  const int n1 = M_TREE * H;           // 4,194,304
  const int n2 = H * H;
  const int n3 = H * KPAD;
  const int n4 = H * 64;
  if (i < n1) { tmsg[i] = f32_to_bf16(__builtin_nontemporal_load(tm + i)); return; }
  int j = i - n1;
  if (j < n2) { whb[j] = f32_to_bf16(wh[j]); return; }
  int k = j - n2;
  if (k < n3) {
    int g = k / KPAD, kk = k - g * KPAD;
    float v = 0.f;
    if (kk < 35)                   v = wo[g * FOUT + kk];
    else if (kk >= 36 && kk < 164) v = wo[g * FOUT + kk - 1];
    wob[k] = f32_to_bf16(v);
    return;
  }
  int m = k - n3;
  if (m < n4) {
    int g = m / 64, kk = m - g * 64;
    wib[m] = (kk < FBOND) ? f32_to_bf16(wi[g * FBOND + kk]) : (unsigned short)0;
  }
}

// ---- h0 = relu(bond_feats @ W_i^T), MFMA, stored bf16 ----
__global__ __launch_bounds__(256, 3) void wi_gemm(const float* __restrict__ bond_feats,
                                                  const unsigned short* __restrict__ wib,
                                                  unsigned short* __restrict__ h0) {
  __shared__ unsigned short sF[128][72];
  const int t = threadIdx.x;
  const int lane = t & 63;
  const int wave = t >> 6;
  const int n16 = lane & 15;
  const int quad = lane >> 4;
  const int b0 = blockIdx.x * 128;

  for (int i = t; i < 128 * FBOND; i += 256) {
    int b = i / FBOND, f = i - b * FBOND;
    sF[b][f] = f32_to_bf16(__builtin_nontemporal_load(bond_feats + b0 * FBOND + i));
  }
  for (int i = t; i < 128 * 24; i += 256) {
    int b = i / 24, c = 40 + i - b * 24;
    sF[b][c] = 0;
  }
  bf16x8 Bf[2][2];
#pragma unroll
  for (int kt = 0; kt < 2; ++kt)
#pragma unroll
    for (int nt = 0; nt < 2; ++nt)
      Bf[kt][nt] = *(const bf16x8*)(wib + ((wave * 2 + nt) * 16 + n16) * 64 + kt * 32 + quad * 8);
  __syncthreads();

  f32x4 acc[8][2];
  f32x4 zero = {0.f, 0.f, 0.f, 0.f};
#pragma unroll
  for (int mt = 0; mt < 8; ++mt) { acc[mt][0] = zero; acc[mt][1] = zero; }
#pragma unroll
  for (int kt = 0; kt < 2; ++kt)
#pragma unroll
    for (int mt = 0; mt < 8; ++mt) {
      bf16x8 av = *(const bf16x8*)&sF[mt * 16 + n16][kt * 32 + quad * 8];
      acc[mt][0] = __builtin_amdgcn_mfma_f32_16x16x32_bf16(av, Bf[kt][0], acc[mt][0], 0, 0, 0);
      acc[mt][1] = __builtin_amdgcn_mfma_f32_16x16x32_bf16(av, Bf[kt][1], acc[mt][1], 0, 0, 0);
    }
#pragma unroll
  for (int mt = 0; mt < 8; ++mt)
#pragma unroll
    for (int nt = 0; nt < 2; ++nt) {
      const int col = (wave * 2 + nt) * 16 + n16;
#pragma unroll
      for (int r = 0; r < 4; ++r) {
        const int b = b0 + mt * 16 + quad * 4 + r;
        h0[b * H + col] = f32_to_bf16(fmaxf(acc[mt][nt][r], 0.f));
      }
    }
}

// ---- one MP round: gm_out = relu(h0 + gather(msg)@W_h^T) ----
__global__ __launch_bounds__(256, 4) void mp_step(const unsigned short* __restrict__ gm_in,
                                                  unsigned short* __restrict__ gm_out,
                                                  const unsigned short* __restrict__ h0,
                                                  const unsigned short* __restrict__ tmsg,
                                                  const int* __restrict__ bond_graph,
                                                  const unsigned short* __restrict__ whb) {
  __shared__ unsigned short snei[TB][136];   // stride 272 B: 16B-aligned, 2-way banks (free)
  __shared__ int sBG[TB * MAXNB];
  const int t = threadIdx.x;
  const int lane = t & 63;
  const int wave = t >> 6;
  const int n16 = lane & 15;
  const int quad = lane >> 4;
  const int b0 = blockIdx.x * TB;

  // stage indices, non-temporal (single-touch stream)
  for (int i = t; i < TB * MAXNB; i += 256)
    sBG[i] = __builtin_nontemporal_load(bond_graph + b0 * MAXNB + i);
  __syncthreads();

  const unsigned short* gsh = gm_in - (size_t)M_TREE * H;
  // gather: indices are wave-uniform -> scalarize address math via readfirstlane
  for (int lb = wave * 2; lb < TB; lb += 8) {
    unsigned int u[2][MAXNB];
#pragma unroll
    for (int p = 0; p < 2; ++p) {
      const int* ig = &sBG[(lb + p) * MAXNB];
#pragma unroll
      for (int j = 0; j < MAXNB; ++j) {
        int idx = __builtin_amdgcn_readfirstlane(ig[j]);
        const unsigned short* r = ((idx < M_TREE) ? tmsg : gsh) + (size_t)idx * H;
        u[p][j] = *(const unsigned int*)(r + 2 * lane);   // cached: table stays in L3
      }
    }
#pragma unroll
    for (int p = 0; p < 2; ++p) {
      float a0 = 0.f, a1 = 0.f;
#pragma unroll
      for (int j = 0; j < MAXNB; ++j) {
        a0 += __uint_as_float(u[p][j] << 16);
        a1 += __uint_as_float(u[p][j] & 0xFFFF0000u);
      }
      unsigned int packed = ((unsigned int)f32_to_bf16(a1) << 16) | (unsigned int)f32_to_bf16(a0);
      *(unsigned int*)&snei[lb + p][2 * lane] = packed;
    }
  }

  // W_h^T fragments (loaded after gather to cut register overlap)
  bf16x8 Bf[4][2];
#pragma unroll
  for (int kt = 0; kt < 4; ++kt)
#pragma unroll
    for (int nt = 0; nt < 2; ++nt)
      Bf[kt][nt] = *(const bf16x8*)(whb + ((wave * 2 + nt) * 16 + n16) * H + kt * 32 + quad * 8);
  __syncthreads();

  f32x4 acc[8][2];
  f32x4 zero = {0.f, 0.f, 0.f, 0.f};
#pragma unroll
  for (int mt = 0; mt < 8; ++mt) { acc[mt][0] = zero; acc[mt][1] = zero; }
#pragma unroll
  for (int kt = 0; kt < 4; ++kt)
#pragma unroll
    for (int mt = 0; mt < 8; ++mt) {
      bf16x8 av = *(const bf16x8*)&snei[mt * 16 + n16][kt * 32 + quad * 8];
      acc[mt][0] = __builtin_amdgcn_mfma_f32_16x16x32_bf16(av, Bf[kt][0], acc[mt][0], 0, 0, 0);
      acc[mt][1] = __builtin_amdgcn_mfma_f32_16x16x32_bf16(av, Bf[kt][1], acc[mt][1], 0, 0, 0);
    }
  __syncthreads();   // all MFMA reads of snei done

  // stage acc -> snei as bf16 (each wave owns 2 col-tiles, all rows)
#pragma unroll
  for (int mt = 0; mt < 8; ++mt)
#pragma unroll
    for (int nt = 0; nt < 2; ++nt) {
      const int col = (wave * 2 + nt) * 16 + n16;
#pragma unroll
      for (int r = 0; r < 4; ++r)
        snei[mt * 16 + quad * 4 + r][col] = f32_to_bf16(acc[mt][nt][r]);
    }
  __syncthreads();

  // vectorized epilogue: out = relu(h0 + acc), 16 B per op, NT on h0.
  // tile = 128 rows x 16 ushort8-chunks = 2048 chunks -> 8 per thread.
  const size_t gbase = (size_t)b0 * H;
#pragma unroll
  for (int c = 0; c < 8; ++c) {
    int fl = c * 256 + t;          // chunk id, 0..2047
    int row = fl >> 4;
    int col = (fl & 15) * 8;
    u32x4 a4 = *(const u32x4*)&snei[row][col];
    u32x4 h4 = __builtin_nontemporal_load((const u32x4*)(h0 + gbase + (size_t)row * H + col));
    u32x4 o4;
    o4.x = bfpair_addrelu(a4.x, h4.x);
    o4.y = bfpair_addrelu(a4.y, h4.y);
    o4.z = bfpair_addrelu(a4.z, h4.z);
    o4.w = bfpair_addrelu(a4.w, h4.w);
    *(u32x4*)(gm_out + gbase + (size_t)row * H + col) = o4;  // cached: next round's table
  }
}

// ---- readout: 128 atoms (4 mols)/block, MFMA over K=192 ----
__global__ __launch_bounds__(256, 3) void readout(const float* __restrict__ atom_feats,
                                                  const unsigned short* __restrict__ gm,
                                                  const unsigned short* __restrict__ tmsg,
                                                  const int* __restrict__ atom_graph,
                                                  const unsigned short* __restrict__ wob,
                                                  const float* __restrict__ b_o,
                                                  float* __restrict__ out) {
  __shared__ unsigned short sA[128][200];
  __shared__ int sAG[128 * MAXNB];
  const int t = threadIdx.x;
  const int lane = t & 63;
  const int wave = t >> 6;
  const int n16 = lane & 15;
  const int quad = lane >> 4;
  const int blk = blockIdx.x;
  const int abase = blk * 128;

  for (int i = t; i < 128 * MAXNB; i += 256)
    sAG[i] = __builtin_nontemporal_load(atom_graph + abase * MAXNB + i);
  for (int i = t; i < 128 * FATOM; i += 256) {
    int a = i / FATOM, f = i - a * FATOM;
    sA[a][f] = f32_to_bf16(__builtin_nontemporal_load(atom_feats + abase * FATOM + i));
  }
  if (t < 128) sA[t][35] = 0;
  for (int i = t; i < 128 * 28; i += 256) {
    int a = i / 28, c = 164 + i - a * 28;
    sA[a][c] = 0;
  }
  __syncthreads();

  const unsigned short* gsh = gm - (size_t)M_TREE * H;
  for (int la = wave * 2; la < 128; la += 8) {
    unsigned int u[2][MAXNB];
#pragma unroll
    for (int p = 0; p < 2; ++p) {
      const int* ig = &sAG[(la + p) * MAXNB];
#pragma unroll
      for (int j = 0; j < MAXNB; ++j) {
        int idx = __builtin_amdgcn_readfirstlane(ig[j]);
        const unsigned short* r = ((idx < M_TREE) ? tmsg : gsh) + (size_t)idx * H;
        u[p][j] = *(const unsigned int*)(r + 2 * lane);
      }
    }
#pragma unroll
    for (int p = 0; p < 2; ++p) {
      float a0 = 0.f, a1 = 0.f;
#pragma unroll
      for (int j = 0; j < MAXNB; ++j) {
        a0 += __uint_as_float(u[p][j] << 16);
        a1 += __uint_as_float(u[p][j] & 0xFFFF0000u);
      }
      unsigned int packed = ((unsigned int)f32_to_bf16(a1) << 16) | (unsigned int)f32_to_bf16(a0);
      *(unsigned int*)&sA[la + p][36 + 2 * lane] = packed;
    }
  }

  bf16x8 Bf[6][2];
#pragma unroll
  for (int kt = 0; kt < 6; ++kt)
#pragma unroll
    for (int nt = 0; nt < 2; ++nt)
      Bf[kt][nt] = *(const bf16x8*)(wob + ((wave * 2 + nt) * 16 + n16) * KPAD + kt * 32 + quad * 8);
  __syncthreads();

  f32x4 acc[8][2];
  f32x4 zero = {0.f, 0.f, 0.f, 0.f};
#pragma unroll
  for (int mt = 0; mt < 8; ++mt) { acc[mt][0] = zero; acc[mt][1] = zero; }
#pragma unroll
  for (int kt = 0; kt < 6; ++kt)
#pragma unroll
    for (int mt = 0; mt < 8; ++mt) {
      bf16x8 av = *(const bf16x8*)&sA[mt * 16 + n16][kt * 32 + quad * 8];
      acc[mt][0] = __builtin_amdgcn_mfma_f32_16x16x32_bf16(av, Bf[kt][0], acc[mt][0], 0, 0, 0);
      acc[mt][1] = __builtin_amdgcn_mfma_f32_16x16x32_bf16(av, Bf[kt][1], acc[mt][1], 0, 0, 0);
    }

  float bo[2] = { b_o[(wave * 2) * 16 + n16], b_o[(wave * 2 + 1) * 16 + n16] };
  float part[4][2] = {{0.f,0.f},{0.f,0.f},{0.f,0.f},{0.f,0.f}};
#pragma unroll
  for (int mt = 0; mt < 8; ++mt)
#pragma unroll
    for (int nt = 0; nt < 2; ++nt)
#pragma unroll
      for (int r = 0; r < 4; ++r)
        part[mt >> 1][nt] += fmaxf(acc[mt][nt][r] + bo[nt], 0.f);
#pragma unroll
  for (int mol = 0; mol < 4; ++mol)
#pragma unroll
    for (int nt = 0; nt < 2; ++nt) {
      float p = part[mol][nt];
      p += __shfl_xor(p, 16);
      p += __shfl_xor(p, 32);
      if (lane < 16)
        out[(blk * 4 + mol) * H + (wave * 2 + nt) * 16 + lane] = p * (1.0f / APM);
    }
}

extern "C" void kernel_launch(void* const* d_in, const int* in_sizes, int n_in,
                              void* d_out, int out_size, void* d_ws, size_t ws_size,
                              hipStream_t stream) {
  (void)in_sizes; (void)n_in; (void)out_size; (void)ws_size;
  const float* atom_feats   = (const float*)d_in[0];
  const float* bond_feats   = (const float*)d_in[1];
  const float* tree_message = (const float*)d_in[2];
  const int*   atom_graph   = (const int*)d_in[3];
  const int*   bond_graph   = (const int*)d_in[4];
  const float* W_i = (const float*)d_in[6];
  const float* W_h = (const float*)d_in[7];
  const float* W_o = (const float*)d_in[8];
  const float* b_o = (const float*)d_in[9];
  float* out = (float*)d_out;

  char* ws = (char*)d_ws;
  unsigned short* tmsg = (unsigned short*)(ws);                    //  8,388,608 B
  unsigned short* whb  = (unsigned short*)(ws + 8388608);
  unsigned short* wob  = (unsigned short*)(ws + 8421376);
  unsigned short* wib  = (unsigned short*)(ws + 8470528);
  unsigned short* h0   = (unsigned short*)(ws + 8486912);          // 67,108,864 B
  unsigned short* gm0  = (unsigned short*)(ws + 75595776);
  unsigned short* gm1  = (unsigned short*)(ws + 142704640);

  prep<<<16576, 256, 0, stream>>>(tree_message, W_h, W_o, W_i, tmsg, whb, wob, wib);
  wi_gemm<<<NBOND / 128, 256, 0, stream>>>(bond_feats, wib, h0);
  mp_step<<<NBOND / TB, 256, 0, stream>>>(h0,  gm0, h0, tmsg, bond_graph, whb);
  mp_step<<<NBOND / TB, 256, 0, stream>>>(gm0, gm1, h0, tmsg, bond_graph, whb);
  mp_step<<<NBOND / TB, 256, 0, stream>>>(gm1, gm0, h0, tmsg, bond_graph, whb);
  mp_step<<<NBOND / TB, 256, 0, stream>>>(gm0, gm1, h0, tmsg, bond_graph, whb);
  mp_step<<<NBOND / TB, 256, 0, stream>>>(gm1, gm0, h0, tmsg, bond_graph, whb);
  readout<<<NATOM / 128, 256, 0, stream>>>(atom_feats, gm0, tmsg, atom_graph, wob, b_o, out);
}

// Round 6
// 775.093 us; speedup vs baseline: 1.4913x; 1.0481x over previous
//
#include <hip/hip_runtime.h>

// ---- problem constants (fixed shapes from setup_inputs) ----
#define H       128
#define MAXNB   10
#define M_TREE  32768
#define NBOND   262144
#define NATOM   131072
#define FATOM   35
#define FBOND   40      // ATOM_FDIM + BOND_FDIM
#define FOUT    163     // ATOM_FDIM + HIDDEN
#define KPAD    192     // FOUT padded (zero col at 35) to 6 k-tiles
#define NMOLS   4096
#define APM     32
#define TB      64      // bonds per block in mp_step (small tile -> 6 blocks/CU)

typedef __bf16 bf16x8 __attribute__((ext_vector_type(8)));
typedef float  f32x4  __attribute__((ext_vector_type(4)));
typedef unsigned int u32x4 __attribute__((ext_vector_type(4)));   // native vec for NT builtins

__device__ __forceinline__ unsigned short f32_to_bf16(float f) {
  unsigned int u = __float_as_uint(f);
  u += 0x7FFFu + ((u >> 16) & 1u);   // RNE (no NaN in this data)
  return (unsigned short)(u >> 16);
}
__device__ __forceinline__ float bf16u_to_f32(unsigned short h) {
  return __uint_as_float(((unsigned int)h) << 16);
}
// packed pair: relu(bf16(a) + bf16(h)) -> packed bf16
__device__ __forceinline__ unsigned int bfpair_addrelu(unsigned int a, unsigned int h) {
  float a0 = __uint_as_float(a << 16), a1 = __uint_as_float(a & 0xFFFF0000u);
  float h0v = __uint_as_float(h << 16), h1v = __uint_as_float(h & 0xFFFF0000u);
  float r0 = fmaxf(a0 + h0v, 0.f), r1 = fmaxf(a1 + h1v, 0.f);
  return ((unsigned int)f32_to_bf16(r1) << 16) | (unsigned int)f32_to_bf16(r0);
}

// ---- prep: bf16 conversions + padded weight layouts ----
__global__ __launch_bounds__(256) void prep(const float* __restrict__ tm,
                                            const float* __restrict__ wh,
                                            const float* __restrict__ wo,
                                            const float* __restrict__ wi,
                                            unsigned short* __restrict__ tmsg,
                                            unsigned short* __restrict__ whb,
                                            unsigned short* __restrict__ wob,
                                            unsigned short* __restrict__ wib) {
  int i = blockIdx.x * 256 + threadIdx.x;
  const int n1 = M_TREE * H;           // 4,194,304
  const int n2 = H * H;
  const int n3 = H * KPAD;
  const int n4 = H * 64;
  if (i < n1) { tmsg[i] = f32_to_bf16(__builtin_nontemporal_load(tm + i)); return; }
  int j = i - n1;
  if (j < n2) { whb[j] = f32_to_bf16(wh[j]); return; }
  int k = j - n2;
  if (k < n3) {
    int g = k / KPAD, kk = k - g * KPAD;
    float v = 0.f;
    if (kk < 35)                   v = wo[g * FOUT + kk];
    else if (kk >= 36 && kk < 164) v = wo[g * FOUT + kk - 1];
    wob[k] = f32_to_bf16(v);
    return;
  }
  int m = k - n3;
  if (m < n4) {
    int g = m / 64, kk = m - g * 64;
    wib[m] = (kk < FBOND) ? f32_to_bf16(wi[g * FBOND + kk]) : (unsigned short)0;
  }
}

// ---- h0 = relu(bond_feats @ W_i^T), MFMA, stored bf16 ----
__global__ __launch_bounds__(256, 3) void wi_gemm(const float* __restrict__ bond_feats,
                                                  const unsigned short* __restrict__ wib,
                                                  unsigned short* __restrict__ h0) {
  __shared__ unsigned short sF[128][72];
  const int t = threadIdx.x;
  const int lane = t & 63;
  const int wave = t >> 6;
  const int n16 = lane & 15;
  const int quad = lane >> 4;
  const int b0 = blockIdx.x * 128;

  for (int i = t; i < 128 * FBOND; i += 256) {
    int b = i / FBOND, f = i - b * FBOND;
    sF[b][f] = f32_to_bf16(__builtin_nontemporal_load(bond_feats + b0 * FBOND + i));
  }
  for (int i = t; i < 128 * 24; i += 256) {
    int b = i / 24, c = 40 + i - b * 24;
    sF[b][c] = 0;
  }
  bf16x8 Bf[2][2];
#pragma unroll
  for (int kt = 0; kt < 2; ++kt)
#pragma unroll
    for (int nt = 0; nt < 2; ++nt)
      Bf[kt][nt] = *(const bf16x8*)(wib + ((wave * 2 + nt) * 16 + n16) * 64 + kt * 32 + quad * 8);
  __syncthreads();

  f32x4 acc[8][2];
  f32x4 zero = {0.f, 0.f, 0.f, 0.f};
#pragma unroll
  for (int mt = 0; mt < 8; ++mt) { acc[mt][0] = zero; acc[mt][1] = zero; }
#pragma unroll
  for (int kt = 0; kt < 2; ++kt)
#pragma unroll
    for (int mt = 0; mt < 8; ++mt) {
      bf16x8 av = *(const bf16x8*)&sF[mt * 16 + n16][kt * 32 + quad * 8];
      acc[mt][0] = __builtin_amdgcn_mfma_f32_16x16x32_bf16(av, Bf[kt][0], acc[mt][0], 0, 0, 0);
      acc[mt][1] = __builtin_amdgcn_mfma_f32_16x16x32_bf16(av, Bf[kt][1], acc[mt][1], 0, 0, 0);
    }
#pragma unroll
  for (int mt = 0; mt < 8; ++mt)
#pragma unroll
    for (int nt = 0; nt < 2; ++nt) {
      const int col = (wave * 2 + nt) * 16 + n16;
#pragma unroll
      for (int r = 0; r < 4; ++r) {
        const int b = b0 + mt * 16 + quad * 4 + r;
        h0[b * H + col] = f32_to_bf16(fmaxf(acc[mt][nt][r], 0.f));
      }
    }
}

// ---- one MP round: gm_out = relu(h0 + gather(msg)@W_h^T) ----
// TB=64: LDS 19968 B -> 6+ blocks/CU; gather latency hidden by occupancy
__global__ __launch_bounds__(256, 6) void mp_step(const unsigned short* __restrict__ gm_in,
                                                  unsigned short* __restrict__ gm_out,
                                                  const unsigned short* __restrict__ h0,
                                                  const unsigned short* __restrict__ tmsg,
                                                  const int* __restrict__ bond_graph,
                                                  const unsigned short* __restrict__ whb) {
  __shared__ unsigned short snei[TB][136];   // 17408 B
  __shared__ int sBG[TB * MAXNB];            //  2560 B
  const int t = threadIdx.x;
  const int lane = t & 63;
  const int wave = t >> 6;
  const int n16 = lane & 15;
  const int quad = lane >> 4;
  const int b0 = blockIdx.x * TB;

  // stage indices (cached: re-read every round, lives in L3)
  for (int i = t; i < TB * MAXNB; i += 256) sBG[i] = bond_graph[b0 * MAXNB + i];
  __syncthreads();

  const unsigned short* gsh = gm_in - (size_t)M_TREE * H;
  // gather: wave-uniform indices -> SALU addressing; 20 row-loads in flight
  for (int lb = wave * 2; lb < TB; lb += 8) {
    unsigned int u[2][MAXNB];
#pragma unroll
    for (int p = 0; p < 2; ++p) {
      const int* ig = &sBG[(lb + p) * MAXNB];
#pragma unroll
      for (int j = 0; j < MAXNB; ++j) {
        int idx = __builtin_amdgcn_readfirstlane(ig[j]);
        const unsigned short* r = ((idx < M_TREE) ? tmsg : gsh) + (size_t)idx * H;
        u[p][j] = *(const unsigned int*)(r + 2 * lane);
      }
    }
#pragma unroll
    for (int p = 0; p < 2; ++p) {
      float a0 = 0.f, a1 = 0.f;
#pragma unroll
      for (int j = 0; j < MAXNB; ++j) {
        a0 += __uint_as_float(u[p][j] << 16);
        a1 += __uint_as_float(u[p][j] & 0xFFFF0000u);
      }
      unsigned int packed = ((unsigned int)f32_to_bf16(a1) << 16) | (unsigned int)f32_to_bf16(a0);
      *(unsigned int*)&snei[lb + p][2 * lane] = packed;
    }
  }

  // W_h^T fragments (after gather to limit register overlap): 32 VGPRs
  bf16x8 Bf[4][2];
#pragma unroll
  for (int kt = 0; kt < 4; ++kt)
#pragma unroll
    for (int nt = 0; nt < 2; ++nt)
      Bf[kt][nt] = *(const bf16x8*)(whb + ((wave * 2 + nt) * 16 + n16) * H + kt * 32 + quad * 8);
  __syncthreads();

  f32x4 acc[4][2];
  f32x4 zero = {0.f, 0.f, 0.f, 0.f};
#pragma unroll
  for (int mt = 0; mt < 4; ++mt) { acc[mt][0] = zero; acc[mt][1] = zero; }
#pragma unroll
  for (int kt = 0; kt < 4; ++kt)
#pragma unroll
    for (int mt = 0; mt < 4; ++mt) {
      bf16x8 av = *(const bf16x8*)&snei[mt * 16 + n16][kt * 32 + quad * 8];
      acc[mt][0] = __builtin_amdgcn_mfma_f32_16x16x32_bf16(av, Bf[kt][0], acc[mt][0], 0, 0, 0);
      acc[mt][1] = __builtin_amdgcn_mfma_f32_16x16x32_bf16(av, Bf[kt][1], acc[mt][1], 0, 0, 0);
    }
  __syncthreads();   // all MFMA reads of snei done

  // stage acc -> snei as bf16 (each wave owns 2 col-tiles, all rows)
#pragma unroll
  for (int mt = 0; mt < 4; ++mt)
#pragma unroll
    for (int nt = 0; nt < 2; ++nt) {
      const int col = (wave * 2 + nt) * 16 + n16;
#pragma unroll
      for (int r = 0; r < 4; ++r)
        snei[mt * 16 + quad * 4 + r][col] = f32_to_bf16(acc[mt][nt][r]);
    }
  __syncthreads();

  // vectorized epilogue: out = relu(h0 + acc); 64 rows x 16 chunks = 1024 -> 4/thread
  const size_t gbase = (size_t)b0 * H;
#pragma unroll
  for (int c = 0; c < 4; ++c) {
    int fl = c * 256 + t;
    int row = fl >> 4;
    int col = (fl & 15) * 8;
    u32x4 a4 = *(const u32x4*)&snei[row][col];
    u32x4 h4 = *(const u32x4*)(h0 + gbase + (size_t)row * H + col);   // cached: L3-resident
    u32x4 o4;
    o4.x = bfpair_addrelu(a4.x, h4.x);
    o4.y = bfpair_addrelu(a4.y, h4.y);
    o4.z = bfpair_addrelu(a4.z, h4.z);
    o4.w = bfpair_addrelu(a4.w, h4.w);
    *(u32x4*)(gm_out + gbase + (size_t)row * H + col) = o4;
  }
}

// ---- readout: 128 atoms (4 mols)/block, MFMA over K=192 ----
__global__ __launch_bounds__(256, 3) void readout(const float* __restrict__ atom_feats,
                                                  const unsigned short* __restrict__ gm,
                                                  const unsigned short* __restrict__ tmsg,
                                                  const int* __restrict__ atom_graph,
                                                  const unsigned short* __restrict__ wob,
                                                  const float* __restrict__ b_o,
                                                  float* __restrict__ out) {
  __shared__ unsigned short sA[128][200];
  __shared__ int sAG[128 * MAXNB];
  const int t = threadIdx.x;
  const int lane = t & 63;
  const int wave = t >> 6;
  const int n16 = lane & 15;
  const int quad = lane >> 4;
  const int blk = blockIdx.x;
  const int abase = blk * 128;

  for (int i = t; i < 128 * MAXNB; i += 256)
    sAG[i] = __builtin_nontemporal_load(atom_graph + abase * MAXNB + i);
  for (int i = t; i < 128 * FATOM; i += 256) {
    int a = i / FATOM, f = i - a * FATOM;
    sA[a][f] = f32_to_bf16(__builtin_nontemporal_load(atom_feats + abase * FATOM + i));
  }
  if (t < 128) sA[t][35] = 0;
  for (int i = t; i < 128 * 28; i += 256) {
    int a = i / 28, c = 164 + i - a * 28;
    sA[a][c] = 0;
  }
  __syncthreads();

  const unsigned short* gsh = gm - (size_t)M_TREE * H;
  for (int la = wave * 2; la < 128; la += 8) {
    unsigned int u[2][MAXNB];
#pragma unroll
    for (int p = 0; p < 2; ++p) {
      const int* ig = &sAG[(la + p) * MAXNB];
#pragma unroll
      for (int j = 0; j < MAXNB; ++j) {
        int idx = __builtin_amdgcn_readfirstlane(ig[j]);
        const unsigned short* r = ((idx < M_TREE) ? tmsg : gsh) + (size_t)idx * H;
        u[p][j] = *(const unsigned int*)(r + 2 * lane);
      }
    }
#pragma unroll
    for (int p = 0; p < 2; ++p) {
      float a0 = 0.f, a1 = 0.f;
#pragma unroll
      for (int j = 0; j < MAXNB; ++j) {
        a0 += __uint_as_float(u[p][j] << 16);
        a1 += __uint_as_float(u[p][j] & 0xFFFF0000u);
      }
      unsigned int packed = ((unsigned int)f32_to_bf16(a1) << 16) | (unsigned int)f32_to_bf16(a0);
      *(unsigned int*)&sA[la + p][36 + 2 * lane] = packed;
    }
  }

  bf16x8 Bf[6][2];
#pragma unroll
  for (int kt = 0; kt < 6; ++kt)
#pragma unroll
    for (int nt = 0; nt < 2; ++nt)
      Bf[kt][nt] = *(const bf16x8*)(wob + ((wave * 2 + nt) * 16 + n16) * KPAD + kt * 32 + quad * 8);
  __syncthreads();

  f32x4 acc[8][2];
  f32x4 zero = {0.f, 0.f, 0.f, 0.f};
#pragma unroll
  for (int mt = 0; mt < 8; ++mt) { acc[mt][0] = zero; acc[mt][1] = zero; }
#pragma unroll
  for (int kt = 0; kt < 6; ++kt)
#pragma unroll
    for (int mt = 0; mt < 8; ++mt) {
      bf16x8 av = *(const bf16x8*)&sA[mt * 16 + n16][kt * 32 + quad * 8];
      acc[mt][0] = __builtin_amdgcn_mfma_f32_16x16x32_bf16(av, Bf[kt][0], acc[mt][0], 0, 0, 0);
      acc[mt][1] = __builtin_amdgcn_mfma_f32_16x16x32_bf16(av, Bf[kt][1], acc[mt][1], 0, 0, 0);
    }

  float bo[2] = { b_o[(wave * 2) * 16 + n16], b_o[(wave * 2 + 1) * 16 + n16] };
  float part[4][2] = {{0.f,0.f},{0.f,0.f},{0.f,0.f},{0.f,0.f}};
#pragma unroll
  for (int mt = 0; mt < 8; ++mt)
#pragma unroll
    for (int nt = 0; nt < 2; ++nt)
#pragma unroll
      for (int r = 0; r < 4; ++r)
        part[mt >> 1][nt] += fmaxf(acc[mt][nt][r] + bo[nt], 0.f);
#pragma unroll
  for (int mol = 0; mol < 4; ++mol)
#pragma unroll
    for (int nt = 0; nt < 2; ++nt) {
      float p = part[mol][nt];
      p += __shfl_xor(p, 16);
      p += __shfl_xor(p, 32);
      if (lane < 16)
        out[(blk * 4 + mol) * H + (wave * 2 + nt) * 16 + lane] = p * (1.0f / APM);
    }
}

extern "C" void kernel_launch(void* const* d_in, const int* in_sizes, int n_in,
                              void* d_out, int out_size, void* d_ws, size_t ws_size,
                              hipStream_t stream) {
  (void)in_sizes; (void)n_in; (void)out_size; (void)ws_size;
  const float* atom_feats   = (const float*)d_in[0];
  const float* bond_feats   = (const float*)d_in[1];
  const float* tree_message = (const float*)d_in[2];
  const int*   atom_graph   = (const int*)d_in[3];
  const int*   bond_graph   = (const int*)d_in[4];
  const float* W_i = (const float*)d_in[6];
  const float* W_h = (const float*)d_in[7];
  const float* W_o = (const float*)d_in[8];
  const float* b_o = (const float*)d_in[9];
  float* out = (float*)d_out;

  char* ws = (char*)d_ws;
  unsigned short* tmsg = (unsigned short*)(ws);                    //  8,388,608 B
  unsigned short* whb  = (unsigned short*)(ws + 8388608);
  unsigned short* wob  = (unsigned short*)(ws + 8421376);
  unsigned short* wib  = (unsigned short*)(ws + 8470528);
  unsigned short* h0   = (unsigned short*)(ws + 8486912);          // 67,108,864 B
  unsigned short* gm0  = (unsigned short*)(ws + 75595776);
  unsigned short* gm1  = (unsigned short*)(ws + 142704640);

  prep<<<16576, 256, 0, stream>>>(tree_message, W_h, W_o, W_i, tmsg, whb, wob, wib);
  wi_gemm<<<NBOND / 128, 256, 0, stream>>>(bond_feats, wib, h0);
  mp_step<<<NBOND / TB, 256, 0, stream>>>(h0,  gm0, h0, tmsg, bond_graph, whb);
  mp_step<<<NBOND / TB, 256, 0, stream>>>(gm0, gm1, h0, tmsg, bond_graph, whb);
  mp_step<<<NBOND / TB, 256, 0, stream>>>(gm1, gm0, h0, tmsg, bond_graph, whb);
  mp_step<<<NBOND / TB, 256, 0, stream>>>(gm0, gm1, h0, tmsg, bond_graph, whb);
  mp_step<<<NBOND / TB, 256, 0, stream>>>(gm1, gm0, h0, tmsg, bond_graph, whb);
  readout<<<NATOM / 128, 256, 0, stream>>>(atom_feats, gm0, tmsg, atom_graph, wob, b_o, out);
}

// Round 7
// 762.648 us; speedup vs baseline: 1.5156x; 1.0163x over previous
//
#include <hip/hip_runtime.h>

// ---- problem constants (fixed shapes from setup_inputs) ----
#define H       128
#define MAXNB   10
#define M_TREE  32768
#define NBOND   262144
#define NATOM   131072
#define FATOM   35
#define FBOND   40      // ATOM_FDIM + BOND_FDIM
#define FOUT    163     // ATOM_FDIM + HIDDEN
#define KPAD    192     // FOUT padded (zero col at 35) to 6 k-tiles
#define NMOLS   4096
#define APM     32
#define TB      64      // bonds per block in mp_step
#define TA      64      // atoms per block in readout

typedef __bf16 bf16x8 __attribute__((ext_vector_type(8)));
typedef float  f32x4  __attribute__((ext_vector_type(4)));
typedef unsigned int u32x4 __attribute__((ext_vector_type(4)));

__device__ __forceinline__ unsigned short f32_to_bf16(float f) {
  unsigned int u = __float_as_uint(f);
  u += 0x7FFFu + ((u >> 16) & 1u);   // RNE (no NaN in this data)
  return (unsigned short)(u >> 16);
}
__device__ __forceinline__ float bf16u_to_f32(unsigned short h) {
  return __uint_as_float(((unsigned int)h) << 16);
}
// packed pair: relu(bf16(a) + bf16(h)) -> packed bf16
__device__ __forceinline__ unsigned int bfpair_addrelu(unsigned int a, unsigned int h) {
  float a0 = __uint_as_float(a << 16), a1 = __uint_as_float(a & 0xFFFF0000u);
  float h0v = __uint_as_float(h << 16), h1v = __uint_as_float(h & 0xFFFF0000u);
  float r0 = fmaxf(a0 + h0v, 0.f), r1 = fmaxf(a1 + h1v, 0.f);
  return ((unsigned int)f32_to_bf16(r1) << 16) | (unsigned int)f32_to_bf16(r0);
}

// ---- prep: bf16 conversions + padded weight layouts ----
__global__ __launch_bounds__(256) void prep(const float* __restrict__ tm,
                                            const float* __restrict__ wh,
                                            const float* __restrict__ wo,
                                            const float* __restrict__ wi,
                                            unsigned short* __restrict__ tmsg,
                                            unsigned short* __restrict__ whb,
                                            unsigned short* __restrict__ wob,
                                            unsigned short* __restrict__ wib) {
  int i = blockIdx.x * 256 + threadIdx.x;
  const int n1 = M_TREE * H;           // 4,194,304
  const int n2 = H * H;
  const int n3 = H * KPAD;
  const int n4 = H * 64;
  if (i < n1) { tmsg[i] = f32_to_bf16(__builtin_nontemporal_load(tm + i)); return; }
  int j = i - n1;
  if (j < n2) { whb[j] = f32_to_bf16(wh[j]); return; }
  int k = j - n2;
  if (k < n3) {
    int g = k / KPAD, kk = k - g * KPAD;
    float v = 0.f;
    if (kk < 35)                   v = wo[g * FOUT + kk];
    else if (kk >= 36 && kk < 164) v = wo[g * FOUT + kk - 1];
    wob[k] = f32_to_bf16(v);
    return;
  }
  int m = k - n3;
  if (m < n4) {
    int g = m / 64, kk = m - g * 64;
    wib[m] = (kk < FBOND) ? f32_to_bf16(wi[g * FBOND + kk]) : (unsigned short)0;
  }
}

// ---- h0 = relu(bond_feats @ W_i^T), MFMA, stored bf16 ----
__global__ __launch_bounds__(256, 3) void wi_gemm(const float* __restrict__ bond_feats,
                                                  const unsigned short* __restrict__ wib,
                                                  unsigned short* __restrict__ h0) {
  __shared__ unsigned short sF[128][72];
  const int t = threadIdx.x;
  const int lane = t & 63;
  const int wave = t >> 6;
  const int n16 = lane & 15;
  const int quad = lane >> 4;
  const int b0 = blockIdx.x * 128;

  for (int i = t; i < 128 * FBOND; i += 256) {
    int b = i / FBOND, f = i - b * FBOND;
    sF[b][f] = f32_to_bf16(__builtin_nontemporal_load(bond_feats + b0 * FBOND + i));
  }
  for (int i = t; i < 128 * 24; i += 256) {
    int b = i / 24, c = 40 + i - b * 24;
    sF[b][c] = 0;
  }
  bf16x8 Bf[2][2];
#pragma unroll
  for (int kt = 0; kt < 2; ++kt)
#pragma unroll
    for (int nt = 0; nt < 2; ++nt)
      Bf[kt][nt] = *(const bf16x8*)(wib + ((wave * 2 + nt) * 16 + n16) * 64 + kt * 32 + quad * 8);
  __syncthreads();

  f32x4 acc[8][2];
  f32x4 zero = {0.f, 0.f, 0.f, 0.f};
#pragma unroll
  for (int mt = 0; mt < 8; ++mt) { acc[mt][0] = zero; acc[mt][1] = zero; }
#pragma unroll
  for (int kt = 0; kt < 2; ++kt)
#pragma unroll
    for (int mt = 0; mt < 8; ++mt) {
      bf16x8 av = *(const bf16x8*)&sF[mt * 16 + n16][kt * 32 + quad * 8];
      acc[mt][0] = __builtin_amdgcn_mfma_f32_16x16x32_bf16(av, Bf[kt][0], acc[mt][0], 0, 0, 0);
      acc[mt][1] = __builtin_amdgcn_mfma_f32_16x16x32_bf16(av, Bf[kt][1], acc[mt][1], 0, 0, 0);
    }
#pragma unroll
  for (int mt = 0; mt < 8; ++mt)
#pragma unroll
    for (int nt = 0; nt < 2; ++nt) {
      const int col = (wave * 2 + nt) * 16 + n16;
#pragma unroll
      for (int r = 0; r < 4; ++r) {
        const int b = b0 + mt * 16 + quad * 4 + r;
        h0[b * H + col] = f32_to_bf16(fmaxf(acc[mt][nt][r], 0.f));
      }
    }
}

// ---- one MP round: gm_out = relu(h0 + gather(msg)@W_h^T) ----
// TB=64, 6 blocks/CU; gather 4 bonds/iter -> 40 row-loads in flight per wave
__global__ __launch_bounds__(256, 6) void mp_step(const unsigned short* __restrict__ gm_in,
                                                  unsigned short* __restrict__ gm_out,
                                                  const unsigned short* __restrict__ h0,
                                                  const unsigned short* __restrict__ tmsg,
                                                  const int* __restrict__ bond_graph,
                                                  const unsigned short* __restrict__ whb) {
  __shared__ unsigned short snei[TB][136];   // 17408 B
  __shared__ int sBG[TB * MAXNB];            //  2560 B
  const int t = threadIdx.x;
  const int lane = t & 63;
  const int wave = t >> 6;
  const int n16 = lane & 15;
  const int quad = lane >> 4;
  const int b0 = blockIdx.x * TB;

  for (int i = t; i < TB * MAXNB; i += 256) sBG[i] = bond_graph[b0 * MAXNB + i];
  __syncthreads();

  const unsigned short* gsh = gm_in - (size_t)M_TREE * H;
  // gather: wave-uniform indices -> SALU addressing; 4 bonds/iter = 40 loads in flight
  for (int lb = wave * 4; lb < TB; lb += 16) {
    unsigned int u[4][MAXNB];
#pragma unroll
    for (int p = 0; p < 4; ++p) {
      const int* ig = &sBG[(lb + p) * MAXNB];
#pragma unroll
      for (int j = 0; j < MAXNB; ++j) {
        int idx = __builtin_amdgcn_readfirstlane(ig[j]);
        const unsigned short* r = ((idx < M_TREE) ? tmsg : gsh) + (size_t)idx * H;
        u[p][j] = *(const unsigned int*)(r + 2 * lane);
      }
    }
#pragma unroll
    for (int p = 0; p < 4; ++p) {
      float a0 = 0.f, a1 = 0.f;
#pragma unroll
      for (int j = 0; j < MAXNB; ++j) {
        a0 += __uint_as_float(u[p][j] << 16);
        a1 += __uint_as_float(u[p][j] & 0xFFFF0000u);
      }
      unsigned int packed = ((unsigned int)f32_to_bf16(a1) << 16) | (unsigned int)f32_to_bf16(a0);
      *(unsigned int*)&snei[lb + p][2 * lane] = packed;
    }
  }

  // W_h^T fragments (after gather to limit register overlap): 32 VGPRs
  bf16x8 Bf[4][2];
#pragma unroll
  for (int kt = 0; kt < 4; ++kt)
#pragma unroll
    for (int nt = 0; nt < 2; ++nt)
      Bf[kt][nt] = *(const bf16x8*)(whb + ((wave * 2 + nt) * 16 + n16) * H + kt * 32 + quad * 8);
  __syncthreads();

  f32x4 acc[4][2];
  f32x4 zero = {0.f, 0.f, 0.f, 0.f};
#pragma unroll
  for (int mt = 0; mt < 4; ++mt) { acc[mt][0] = zero; acc[mt][1] = zero; }
#pragma unroll
  for (int kt = 0; kt < 4; ++kt)
#pragma unroll
    for (int mt = 0; mt < 4; ++mt) {
      bf16x8 av = *(const bf16x8*)&snei[mt * 16 + n16][kt * 32 + quad * 8];
      acc[mt][0] = __builtin_amdgcn_mfma_f32_16x16x32_bf16(av, Bf[kt][0], acc[mt][0], 0, 0, 0);
      acc[mt][1] = __builtin_amdgcn_mfma_f32_16x16x32_bf16(av, Bf[kt][1], acc[mt][1], 0, 0, 0);
    }
  __syncthreads();   // all MFMA reads of snei done

  // stage acc -> snei as bf16
#pragma unroll
  for (int mt = 0; mt < 4; ++mt)
#pragma unroll
    for (int nt = 0; nt < 2; ++nt) {
      const int col = (wave * 2 + nt) * 16 + n16;
#pragma unroll
      for (int r = 0; r < 4; ++r)
        snei[mt * 16 + quad * 4 + r][col] = f32_to_bf16(acc[mt][nt][r]);
    }
  __syncthreads();

  // vectorized epilogue: 64 rows x 16 chunks = 1024 -> 4/thread
  const size_t gbase = (size_t)b0 * H;
#pragma unroll
  for (int c = 0; c < 4; ++c) {
    int fl = c * 256 + t;
    int row = fl >> 4;
    int col = (fl & 15) * 8;
    u32x4 a4 = *(const u32x4*)&snei[row][col];
    u32x4 h4 = *(const u32x4*)(h0 + gbase + (size_t)row * H + col);
    u32x4 o4;
    o4.x = bfpair_addrelu(a4.x, h4.x);
    o4.y = bfpair_addrelu(a4.y, h4.y);
    o4.z = bfpair_addrelu(a4.z, h4.z);
    o4.w = bfpair_addrelu(a4.w, h4.w);
    *(u32x4*)(gm_out + gbase + (size_t)row * H + col) = o4;
  }
}

// ---- readout: 64 atoms (2 mols)/block, MFMA over K=192, 4 blocks/CU ----
__global__ __launch_bounds__(256, 4) void readout(const float* __restrict__ atom_feats,
                                                  const unsigned short* __restrict__ gm,
                                                  const unsigned short* __restrict__ tmsg,
                                                  const int* __restrict__ atom_graph,
                                                  const unsigned short* __restrict__ wob,
                                                  const float* __restrict__ b_o,
                                                  float* __restrict__ out) {
  __shared__ unsigned short sA[TA][200];     // 25600 B
  __shared__ int sAG[TA * MAXNB];            //  2560 B
  const int t = threadIdx.x;
  const int lane = t & 63;
  const int wave = t >> 6;
  const int n16 = lane & 15;
  const int quad = lane >> 4;
  const int blk = blockIdx.x;
  const int abase = blk * TA;

  for (int i = t; i < TA * MAXNB; i += 256)
    sAG[i] = __builtin_nontemporal_load(atom_graph + abase * MAXNB + i);
  for (int i = t; i < TA * FATOM; i += 256) {
    int a = i / FATOM, f = i - a * FATOM;
    sA[a][f] = f32_to_bf16(__builtin_nontemporal_load(atom_feats + abase * FATOM + i));
  }
  if (t < TA) sA[t][35] = 0;
  for (int i = t; i < TA * 28; i += 256) {
    int a = i / 28, c = 164 + i - a * 28;
    sA[a][c] = 0;
  }
  __syncthreads();

  const unsigned short* gsh = gm - (size_t)M_TREE * H;
  for (int la = wave * 4; la < TA; la += 16) {
    unsigned int u[4][MAXNB];
#pragma unroll
    for (int p = 0; p < 4; ++p) {
      const int* ig = &sAG[(la + p) * MAXNB];
#pragma unroll
      for (int j = 0; j < MAXNB; ++j) {
        int idx = __builtin_amdgcn_readfirstlane(ig[j]);
        const unsigned short* r = ((idx < M_TREE) ? tmsg : gsh) + (size_t)idx * H;
        u[p][j] = *(const unsigned int*)(r + 2 * lane);
      }
    }
#pragma unroll
    for (int p = 0; p < 4; ++p) {
      float a0 = 0.f, a1 = 0.f;
#pragma unroll
      for (int j = 0; j < MAXNB; ++j) {
        a0 += __uint_as_float(u[p][j] << 16);
        a1 += __uint_as_float(u[p][j] & 0xFFFF0000u);
      }
      unsigned int packed = ((unsigned int)f32_to_bf16(a1) << 16) | (unsigned int)f32_to_bf16(a0);
      *(unsigned int*)&sA[la + p][36 + 2 * lane] = packed;
    }
  }

  bf16x8 Bf[6][2];
#pragma unroll
  for (int kt = 0; kt < 6; ++kt)
#pragma unroll
    for (int nt = 0; nt < 2; ++nt)
      Bf[kt][nt] = *(const bf16x8*)(wob + ((wave * 2 + nt) * 16 + n16) * KPAD + kt * 32 + quad * 8);
  __syncthreads();

  f32x4 acc[4][2];
  f32x4 zero = {0.f, 0.f, 0.f, 0.f};
#pragma unroll
  for (int mt = 0; mt < 4; ++mt) { acc[mt][0] = zero; acc[mt][1] = zero; }
#pragma unroll
  for (int kt = 0; kt < 6; ++kt)
#pragma unroll
    for (int mt = 0; mt < 4; ++mt) {
      bf16x8 av = *(const bf16x8*)&sA[mt * 16 + n16][kt * 32 + quad * 8];
      acc[mt][0] = __builtin_amdgcn_mfma_f32_16x16x32_bf16(av, Bf[kt][0], acc[mt][0], 0, 0, 0);
      acc[mt][1] = __builtin_amdgcn_mfma_f32_16x16x32_bf16(av, Bf[kt][1], acc[mt][1], 0, 0, 0);
    }

  // bias + relu per atom, then per-mol partial sums (mol = mt>>1; 2 mols/block)
  float bo[2] = { b_o[(wave * 2) * 16 + n16], b_o[(wave * 2 + 1) * 16 + n16] };
  float part[2][2] = {{0.f,0.f},{0.f,0.f}};
#pragma unroll
  for (int mt = 0; mt < 4; ++mt)
#pragma unroll
    for (int nt = 0; nt < 2; ++nt)
#pragma unroll
      for (int r = 0; r < 4; ++r)
        part[mt >> 1][nt] += fmaxf(acc[mt][nt][r] + bo[nt], 0.f);
#pragma unroll
  for (int mol = 0; mol < 2; ++mol)
#pragma unroll
    for (int nt = 0; nt < 2; ++nt) {
      float p = part[mol][nt];
      p += __shfl_xor(p, 16);
      p += __shfl_xor(p, 32);
      if (lane < 16)
        out[(blk * 2 + mol) * H + (wave * 2 + nt) * 16 + lane] = p * (1.0f / APM);
    }
}

extern "C" void kernel_launch(void* const* d_in, const int* in_sizes, int n_in,
                              void* d_out, int out_size, void* d_ws, size_t ws_size,
                              hipStream_t stream) {
  (void)in_sizes; (void)n_in; (void)out_size; (void)ws_size;
  const float* atom_feats   = (const float*)d_in[0];
  const float* bond_feats   = (const float*)d_in[1];
  const float* tree_message = (const float*)d_in[2];
  const int*   atom_graph   = (const int*)d_in[3];
  const int*   bond_graph   = (const int*)d_in[4];
  const float* W_i = (const float*)d_in[6];
  const float* W_h = (const float*)d_in[7];
  const float* W_o = (const float*)d_in[8];
  const float* b_o = (const float*)d_in[9];
  float* out = (float*)d_out;

  char* ws = (char*)d_ws;
  unsigned short* tmsg = (unsigned short*)(ws);                    //  8,388,608 B
  unsigned short* whb  = (unsigned short*)(ws + 8388608);
  unsigned short* wob  = (unsigned short*)(ws + 8421376);
  unsigned short* wib  = (unsigned short*)(ws + 8470528);
  unsigned short* h0   = (unsigned short*)(ws + 8486912);          // 67,108,864 B
  unsigned short* gm0  = (unsigned short*)(ws + 75595776);
  unsigned short* gm1  = (unsigned short*)(ws + 142704640);

  prep<<<16576, 256, 0, stream>>>(tree_message, W_h, W_o, W_i, tmsg, whb, wob, wib);
  wi_gemm<<<NBOND / 128, 256, 0, stream>>>(bond_feats, wib, h0);
  mp_step<<<NBOND / TB, 256, 0, stream>>>(h0,  gm0, h0, tmsg, bond_graph, whb);
  mp_step<<<NBOND / TB, 256, 0, stream>>>(gm0, gm1, h0, tmsg, bond_graph, whb);
  mp_step<<<NBOND / TB, 256, 0, stream>>>(gm1, gm0, h0, tmsg, bond_graph, whb);
  mp_step<<<NBOND / TB, 256, 0, stream>>>(gm0, gm1, h0, tmsg, bond_graph, whb);
  mp_step<<<NBOND / TB, 256, 0, stream>>>(gm1, gm0, h0, tmsg, bond_graph, whb);
  readout<<<NATOM / TA, 256, 0, stream>>>(atom_feats, gm0, tmsg, atom_graph, wob, b_o, out);
}